// Round 2
// baseline (220.881 us; speedup 1.0000x reference)
//
#include <hip/hip_runtime.h>
#include <stdint.h>

// Problem constants (fixed by the reference)
#define H 56
#define W 56
#define HW (H * W)          // 3136
#define CIN 256
#define IMG (CIN * HW)      // 802816 elements per image
#define EPS 1e-5f

#define ROWW 8              // u32 words per tile row: 32B = 64 nibbles
#define TR2 30              // tile rows: 28 outputs + 2 halo/padding
#define TSZ (TR2 * ROWW)    // 240 words per tile
#define ATASKS 406          // 29 staged input rows x 14 col-groups
#define BTASKS 392          // 28 output rows x 14 col-groups

// Strict fp32 RN ops, immune to -ffp-contract (inline asm cannot be fused).
// The np reference's exact-zero BN outputs (sign->0) only reproduce with the
// two-rounding chain round(round(x*inv)+bias).
__device__ __forceinline__ float mul_rn(float a, float b) {
    float d; asm("v_mul_f32 %0, %1, %2" : "=v"(d) : "v"(a), "v"(b)); return d;
}
__device__ __forceinline__ float add_rn(float a, float b) {
    float d; asm("v_add_f32 %0, %1, %2" : "=v"(d) : "v"(a), "v"(b)); return d;
}
__device__ __forceinline__ float sub_rn(float a, float b) {
    float d; asm("v_sub_f32 %0, %1, %2" : "=v"(d) : "v"(a), "v"(b)); return d;
}
// Scalar-operand variants: BN constants are block-uniform -> SGPR (src0 may be
// scalar; saves 8 VGPRs). Multiplication/addition commute bit-exactly in RN.
__device__ __forceinline__ float mul_rn_sv(float s, float v) {
    float d; asm("v_mul_f32 %0, %1, %2" : "=v"(d) : "s"(s), "v"(v)); return d;
}
__device__ __forceinline__ float add_rn_sv(float s, float v) {
    float d; asm("v_add_f32 %0, %1, %2" : "=v"(d) : "s"(s), "v"(v)); return d;
}
__device__ __forceinline__ float rfl_f(float x) {
    return __int_as_float(__builtin_amdgcn_readfirstlane(__float_as_int(x)));
}

// ---------------------------------------------------------------------------
// Fused: BN -> ternary sign -> XNOR-popcount grouped 3x3 conv -> shuffle -> +x
// One block per (n-pair, g, row-half): 2 planes {n0, n0+nHalf} x 28 output
// rows. Grid = 16*64*2 = 2048 blocks = exactly 8 blocks/CU; VGPRs forced to 64
// (__launch_bounds__(256,8)) so all 32 waves/CU are resident.
//
// LDS tile per plane-half: 30 rows x 8 u32; tile row rt holds input row
// (half*28 - 1 + rt) as packed 4-bit nibbles. Unwritten first/last tile row
// and nibble cols 56..63 stay zero => z-plane zeros subsume all padding.
//
// Pipeline (per block): plane-1 loads are issued one task at a time, pinned
// with sched_barrier(0) so the compiler cannot sink them to their use; each
// in-flight task (16 VGPRs) is covered by a full phase-B task (~270 instrs).
// ---------------------------------------------------------------------------

struct Stage { float4 q[4]; };

// Issue the 4 float4 loads of one Phase-A task (input row ir, 4-px group cg).
__device__ __forceinline__ void issueA(const float* __restrict__ Xn, int g, int half,
                                       int t, Stage& st) {
    int ar = t / 14;
    int cg = t - ar * 14;
    int ir = ar + half * 27;           // staged input rows: half0 0..28, half1 27..55
    const float* base = Xn + (size_t)(g * 4) * HW + ir * W + cg * 4;
#pragma unroll
    for (int ci = 0; ci < 4; ++ci)
        st.q[ci] = *reinterpret_cast<const float4*>(base + (size_t)ci * HW);
}

// BN + ternary-sign pack of 4 channels x 4 px into (s16, z16).
__device__ __forceinline__ void bn_pack(const Stage& st, const float inv[4], const float bias[4],
                                        uint32_t& s16, uint32_t& z16) {
    s16 = 0u; z16 = 0u;
#pragma unroll
    for (int ci = 0; ci < 4; ++ci) {
        float t0 = add_rn_sv(bias[ci], mul_rn_sv(inv[ci], st.q[ci].x));
        float t1 = add_rn_sv(bias[ci], mul_rn_sv(inv[ci], st.q[ci].y));
        float t2 = add_rn_sv(bias[ci], mul_rn_sv(inv[ci], st.q[ci].z));
        float t3 = add_rn_sv(bias[ci], mul_rn_sv(inv[ci], st.q[ci].w));
        s16 |= ((t0 > 0.f ? 1u : 0u) << ci)        | ((t1 > 0.f ? 1u : 0u) << (4 + ci))
             | ((t2 > 0.f ? 1u : 0u) << (8 + ci))  | ((t3 > 0.f ? 1u : 0u) << (12 + ci));
        z16 |= ((t0 != 0.f ? 1u : 0u) << ci)       | ((t1 != 0.f ? 1u : 0u) << (4 + ci))
             | ((t2 != 0.f ? 1u : 0u) << (8 + ci)) | ((t3 != 0.f ? 1u : 0u) << (12 + ci));
    }
}

// Convert one staged task into the LDS tile.
__device__ __forceinline__ void convA(const Stage& st, const float inv[4], const float bias[4],
                                      uint32_t* s_t, uint32_t* z_t, int t, int half) {
    int ar = t / 14;
    int cg = t - ar * 14;
    int rt = ar + 1 - half;            // tile row: half0 -> 1..29, half1 -> 0..28
    uint32_t s16, z16;
    bn_pack(st, inv, bias, s16, z16);
    reinterpret_cast<uint16_t*>(&s_t[rt * ROWW])[cg] = (uint16_t)s16;
    reinterpret_cast<uint16_t*>(&z_t[rt * ROWW])[cg] = (uint16_t)z16;
}

// One Phase-B task: 6 two-dword LDS reads, XNOR-popcount for 4 filters x 4 px,
// shuffled float4 shortcut + store. Shortcut loads grouped at epilogue start
// (latency covered by 8-wave TLP; keeps peak VGPR inside the 64 budget).
__device__ __forceinline__ void taskB(const uint32_t* s_t, const uint32_t* z_t,
                                      const float* __restrict__ Xn, float* __restrict__ On,
                                      int g, int half, int task,
                                      const uint32_t wsj[4][3], const uint32_t wzj[4][3],
                                      bool full) {
    int hl = task / 14;
    int cg = task - hl * 14;
    int w0 = cg * 4;

    uint64_t vs[3], vz[3];
    int off;
    if (w0 == 0) {
        off = 0;
#pragma unroll
        for (int r = 0; r < 3; ++r) {
            int base = (hl + r) * ROWW;
            vs[r] = (((uint64_t)s_t[base] | ((uint64_t)s_t[base + 1] << 32)) << 4);
            vz[r] = (((uint64_t)z_t[base] | ((uint64_t)z_t[base + 1] << 32)) << 4);
        }
    } else {
        int st = 4 * w0 - 4;
        int i0 = st >> 5;
        off = st & 31;
#pragma unroll
        for (int r = 0; r < 3; ++r) {
            int base = (hl + r) * ROWW + i0;
            vs[r] = ((uint64_t)s_t[base] | ((uint64_t)s_t[base + 1] << 32));
            vz[r] = ((uint64_t)z_t[base] | ((uint64_t)z_t[base + 1] << 32));
        }
    }

    int res[4][4];
    if (full) {
#pragma unroll
        for (int k = 0; k < 4; ++k) {
            int sh = off + 4 * k;
            uint32_t s0 = (uint32_t)(vs[0] >> sh) & 0xFFFu;
            uint32_t s1 = (uint32_t)(vs[1] >> sh) & 0xFFFu;
            uint32_t s2 = (uint32_t)(vs[2] >> sh) & 0xFFFu;
            uint32_t z0 = (uint32_t)(vz[0] >> sh) & 0xFFFu;
            uint32_t z1 = (uint32_t)(vz[1] >> sh) & 0xFFFu;
            uint32_t z2 = (uint32_t)(vz[2] >> sh) & 0xFFFu;
            int vb = __popc(z0) + __popc(z1) + __popc(z2);
#pragma unroll
            for (int j = 0; j < 4; ++j) {
                int pc = __popc((s0 ^ wsj[j][0]) & z0)
                       + __popc((s1 ^ wsj[j][1]) & z1)
                       + __popc((s2 ^ wsj[j][2]) & z2);
                res[j][k] = vb - 2 * pc;
            }
        }
    } else {
#pragma unroll
        for (int k = 0; k < 4; ++k) {
            int sh = off + 4 * k;
            uint32_t s0 = (uint32_t)(vs[0] >> sh) & 0xFFFu;
            uint32_t s1 = (uint32_t)(vs[1] >> sh) & 0xFFFu;
            uint32_t s2 = (uint32_t)(vs[2] >> sh) & 0xFFFu;
            uint32_t z0 = (uint32_t)(vz[0] >> sh) & 0xFFFu;
            uint32_t z1 = (uint32_t)(vz[1] >> sh) & 0xFFFu;
            uint32_t z2 = (uint32_t)(vz[2] >> sh) & 0xFFFu;
#pragma unroll
            for (int j = 0; j < 4; ++j) {
                uint32_t m0 = z0 & wzj[j][0];
                uint32_t m1 = z1 & wzj[j][1];
                uint32_t m2 = z2 & wzj[j][2];
                int vb = __popc(m0) + __popc(m1) + __popc(m2);
                int pc = __popc((s0 ^ wsj[j][0]) & m0)
                       + __popc((s1 ^ wsj[j][1]) & m1)
                       + __popc((s2 ^ wsj[j][2]) & m2);
                res[j][k] = vb - 2 * pc;
            }
        }
    }

    // Epilogue: shuffled channel c' = j*64 + g; float4 shortcut + store.
    size_t pbase = (size_t)(half * 28 + hl) * W + w0;
    float4 sc[4];
#pragma unroll
    for (int j = 0; j < 4; ++j)
        sc[j] = *reinterpret_cast<const float4*>(Xn + (size_t)(j * 64 + g) * HW + pbase);
#pragma unroll
    for (int j = 0; j < 4; ++j) {
        size_t cofs = (size_t)(j * 64 + g) * HW + pbase;
        float4 o;
        o.x = add_rn((float)res[j][0], sc[j].x);
        o.y = add_rn((float)res[j][1], sc[j].y);
        o.z = add_rn((float)res[j][2], sc[j].z);
        o.w = add_rn((float)res[j][3], sc[j].w);
        *reinterpret_cast<float4*>(On + cofs) = o;
    }
}

__global__ __launch_bounds__(256, 8)
void binconv_kernel(const float* __restrict__ X,
                    const float* __restrict__ Wt,
                    const float* __restrict__ gamma,
                    const float* __restrict__ beta,
                    const float* __restrict__ mean,
                    const float* __restrict__ var,
                    float* __restrict__ out, int nHalf) {
    __shared__ uint32_t s_tile[2][TSZ];   // sign nibbles, double-buffered
    __shared__ uint32_t z_tile[2][TSZ];   // nonzero nibbles
    __shared__ uint32_t ws_l[4][3];       // weight sign rows (12-bit)
    __shared__ uint32_t wz_l[4][3];       // weight nz   rows (12-bit)

    const int bx   = blockIdx.x;
    const int half = bx & 1;
    const int g    = (bx >> 1) & 63;
    const int n0   = bx >> 7;
    const int tid  = threadIdx.x;

    // Zero both tile buffers (interiors are overwritten after the barriers).
    for (int i = tid; i < 2 * TSZ; i += 256) {
        (&s_tile[0][0])[i] = 0u;
        (&z_tile[0][0])[i] = 0u;
    }

    const float* Xn0 = X   + (size_t)n0 * IMG;
    const float* Xn1 = X   + (size_t)(n0 + nHalf) * IMG;
    float*       On0 = out + (size_t)n0 * IMG;
    float*       On1 = out + (size_t)(n0 + nHalf) * IMG;

    // Plane-0 staging loads issued first (bulk data; latency hides under the
    // weight pack / BN-const setup below; the first barrier drains them, but
    // they are consumed immediately after anyway).
    Stage a0, a1;
    issueA(Xn0, g, half, tid, a0);
    if (tid < ATASKS - 256) issueA(Xn0, g, half, tid + 256, a1);

    // Threads 0..3 pack this group's 4 filters into 12-bit row patterns.
    // bit = kw*4 + ci  (kw aligns with window nibble: w-1, w, w+1).
    if (tid < 4) {
        const float* wc = Wt + (size_t)(g * 4 + tid) * 36;   // [ci][kh][kw]
        for (int r = 0; r < 3; ++r) {
            uint32_t s = 0, z = 0;
            for (int ci = 0; ci < 4; ++ci)
                for (int kw = 0; kw < 3; ++kw) {
                    float v = wc[ci * 9 + r * 3 + kw];
                    int b = kw * 4 + ci;
                    s |= (v > 0.f  ? 1u : 0u) << b;
                    z |= (v != 0.f ? 1u : 0u) << b;
                }
            ws_l[tid][r] = s; wz_l[tid][r] = z;
        }
    }

    // BN constants (strict np fp32 chain), block-uniform -> SGPRs.
    float inv[4], bias[4];
#pragma unroll
    for (int ci = 0; ci < 4; ++ci) {
        int c = g * 4 + ci;
        float s  = sqrtf(var[c] + EPS);   // correctly rounded
        float r  = 1.0f / s;              // correctly rounded
        float iv = mul_rn(gamma[c], r);
        inv[ci]  = rfl_f(iv);
        bias[ci] = rfl_f(sub_rn(beta[c], mul_rn(mean[c], iv)));
    }

    __syncthreads();                      // zeros + packed weights visible

    convA(a0, inv, bias, s_tile[0], z_tile[0], tid, half);
    if (tid < ATASKS - 256) convA(a1, inv, bias, s_tile[0], z_tile[0], tid + 256, half);

    // Weight masks to SGPRs (block-uniform).
    uint32_t wsj[4][3], wzj[4][3];
    bool full = true;
#pragma unroll
    for (int j = 0; j < 4; ++j)
#pragma unroll
        for (int r = 0; r < 3; ++r) {
            wsj[j][r] = __builtin_amdgcn_readfirstlane(ws_l[j][r]);
            wzj[j][r] = __builtin_amdgcn_readfirstlane(wz_l[j][r]);
            full = full && (wzj[j][r] == 0xFFFu);
        }

    __syncthreads();                      // tile 0 ready

    // --- Pipelined middle: plane-1 loads overlapped with plane-0 compute. ---
    // sched_barrier(0) pins each load-issue above the covering compute block
    // so the compiler cannot sink it to its use (round-1 failure mode).
    issueA(Xn1, g, half, tid, a0);
    __builtin_amdgcn_sched_barrier(0);

    taskB(s_tile[0], z_tile[0], Xn0, On0, g, half, tid, wsj, wzj, full);

    convA(a0, inv, bias, s_tile[1], z_tile[1], tid, half);
    if (tid < ATASKS - 256) issueA(Xn1, g, half, tid + 256, a1);
    __builtin_amdgcn_sched_barrier(0);

    if (tid < BTASKS - 256)
        taskB(s_tile[0], z_tile[0], Xn0, On0, g, half, tid + 256, wsj, wzj, full);

    if (tid < ATASKS - 256) convA(a1, inv, bias, s_tile[1], z_tile[1], tid + 256, half);

    __syncthreads();                      // tile 1 ready

    taskB(s_tile[1], z_tile[1], Xn1, On1, g, half, tid, wsj, wzj, full);
    if (tid < BTASKS - 256)
        taskB(s_tile[1], z_tile[1], Xn1, On1, g, half, tid + 256, wsj, wzj, full);
}

// ---------------------------------------------------------------------------
extern "C" void kernel_launch(void* const* d_in, const int* in_sizes, int n_in,
                              void* d_out, int out_size, void* d_ws, size_t ws_size,
                              hipStream_t stream) {
    const float* X     = (const float*)d_in[0];
    const float* Wt    = (const float*)d_in[1];
    const float* gamma = (const float*)d_in[2];
    const float* beta  = (const float*)d_in[3];
    const float* mean  = (const float*)d_in[4];
    const float* var   = (const float*)d_in[5];
    float* out = (float*)d_out;

    int N     = in_sizes[0] / IMG;    // 32
    int nHalf = N >> 1;               // 16: block handles planes (n, g) and (n+16, g)

    // grid: n-pair (16) x group (64) x row-half (2) = 2048 blocks = 8 per CU
    binconv_kernel<<<nHalf * 64 * 2, 256, 0, stream>>>(X, Wt, gamma, beta, mean, var, out, nHalf);
}

// Round 3
// 211.006 us; speedup vs baseline: 1.0468x; 1.0468x over previous
//
#include <hip/hip_runtime.h>
#include <stdint.h>

// Problem constants (fixed by the reference)
#define H 56
#define W 56
#define HW (H * W)          // 3136
#define CIN 256
#define IMG (CIN * HW)      // 802816 elements per image
#define EPS 1e-5f

#define ROWW 8              // u32 words per tile row: 32B = 64 nibbles
#define TR2 30              // tile rows: 28 outputs + 2 halo/padding
#define TSZ (TR2 * ROWW)    // 240 words per tile
#define ATASKS 406          // 29 staged input rows x 14 col-groups
#define BTASKS 392          // 28 output rows x 14 col-groups

// Strict fp32 RN ops, immune to -ffp-contract (inline asm cannot be fused).
// The np reference's exact-zero BN outputs (sign->0) only reproduce with the
// two-rounding chain round(round(x*inv)+bias).
__device__ __forceinline__ float mul_rn(float a, float b) {
    float d; asm("v_mul_f32 %0, %1, %2" : "=v"(d) : "v"(a), "v"(b)); return d;
}
__device__ __forceinline__ float add_rn(float a, float b) {
    float d; asm("v_add_f32 %0, %1, %2" : "=v"(d) : "v"(a), "v"(b)); return d;
}
__device__ __forceinline__ float sub_rn(float a, float b) {
    float d; asm("v_sub_f32 %0, %1, %2" : "=v"(d) : "v"(a), "v"(b)); return d;
}
// Scalar-operand variants: BN constants are block-uniform -> SGPR (src0 may be
// scalar). Multiplication/addition commute bit-exactly in RN.
__device__ __forceinline__ float mul_rn_sv(float s, float v) {
    float d; asm("v_mul_f32 %0, %1, %2" : "=v"(d) : "s"(s), "v"(v)); return d;
}
__device__ __forceinline__ float add_rn_sv(float s, float v) {
    float d; asm("v_add_f32 %0, %1, %2" : "=v"(d) : "s"(s), "v"(v)); return d;
}
__device__ __forceinline__ float rfl_f(float x) {
    return __int_as_float(__builtin_amdgcn_readfirstlane(__float_as_int(x)));
}

// ---------------------------------------------------------------------------
// Fused: BN -> ternary sign -> XNOR-popcount grouped 3x3 conv -> shuffle -> +x
// One block per (n, g); the plane's 56 rows are processed as two pipelined
// 28-row halves with double-buffered LDS tiles. Grid = 32*64 = 2048 blocks.
// __launch_bounds__(256, 6): ~84-VGPR budget -> no spills (round-2 failure),
// 6 blocks/CU = 24 waves/CU resident.
//
// LDS tile per half: 30 rows x 8 u32; half0 stages input rows 0..28 at tile
// rows 1..29 (row 0 = top pad), half1 stages rows 27..55 at tile rows 0..28
// (row 29 = bottom pad). Halo rows 27/28 are re-fetched by the same block ->
// L1/L2 hit. Unwritten pad rows and nibble cols 56..63 stay zero => z-plane
// zeros subsume all geometric padding.
//
// Pipeline: half-1 loads are issued in two batches, each pinned with
// sched_barrier(0) so the compiler cannot sink them to their use (round-1
// failure mode); each in-flight batch (16 VGPRs) is covered by a full
// phase-B task (~250 instrs).
// ---------------------------------------------------------------------------

struct Stage { float4 q[4]; };

// Issue the 4 float4 loads of one Phase-A task (staged row ar, 4-px group cg).
__device__ __forceinline__ void issueA(const float* __restrict__ Xn, int g, int rowbase,
                                       int t, Stage& st) {
    int ar = t / 14;
    int cg = t - ar * 14;
    int ir = rowbase + ar;             // input row
    const float* base = Xn + (size_t)(g * 4) * HW + ir * W + cg * 4;
#pragma unroll
    for (int ci = 0; ci < 4; ++ci)
        st.q[ci] = *reinterpret_cast<const float4*>(base + (size_t)ci * HW);
}

// BN + ternary-sign pack of 4 channels x 4 px into (s16, z16).
__device__ __forceinline__ void bn_pack(const Stage& st, const float inv[4], const float bias[4],
                                        uint32_t& s16, uint32_t& z16) {
    s16 = 0u; z16 = 0u;
#pragma unroll
    for (int ci = 0; ci < 4; ++ci) {
        float t0 = add_rn_sv(bias[ci], mul_rn_sv(inv[ci], st.q[ci].x));
        float t1 = add_rn_sv(bias[ci], mul_rn_sv(inv[ci], st.q[ci].y));
        float t2 = add_rn_sv(bias[ci], mul_rn_sv(inv[ci], st.q[ci].z));
        float t3 = add_rn_sv(bias[ci], mul_rn_sv(inv[ci], st.q[ci].w));
        s16 |= ((t0 > 0.f ? 1u : 0u) << ci)        | ((t1 > 0.f ? 1u : 0u) << (4 + ci))
             | ((t2 > 0.f ? 1u : 0u) << (8 + ci))  | ((t3 > 0.f ? 1u : 0u) << (12 + ci));
        z16 |= ((t0 != 0.f ? 1u : 0u) << ci)       | ((t1 != 0.f ? 1u : 0u) << (4 + ci))
             | ((t2 != 0.f ? 1u : 0u) << (8 + ci)) | ((t3 != 0.f ? 1u : 0u) << (12 + ci));
    }
}

// Convert one staged task into the LDS tile (tile row = ar + rtoff).
__device__ __forceinline__ void convA(const Stage& st, const float inv[4], const float bias[4],
                                      uint32_t* s_t, uint32_t* z_t, int t, int rtoff) {
    int ar = t / 14;
    int cg = t - ar * 14;
    int rt = ar + rtoff;
    uint32_t s16, z16;
    bn_pack(st, inv, bias, s16, z16);
    reinterpret_cast<uint16_t*>(&s_t[rt * ROWW])[cg] = (uint16_t)s16;
    reinterpret_cast<uint16_t*>(&z_t[rt * ROWW])[cg] = (uint16_t)z16;
}

// One Phase-B task: 6 two-dword LDS reads, XNOR-popcount for 4 filters x 4 px,
// shuffled float4 shortcut + store. Shortcut loads grouped at epilogue start
// (latency covered by 24-wave/CU TLP; keeps peak VGPR inside the budget).
__device__ __forceinline__ void taskB(const uint32_t* s_t, const uint32_t* z_t,
                                      const float* __restrict__ Xn, float* __restrict__ On,
                                      int g, int half, int task,
                                      const uint32_t wsj[4][3], const uint32_t wzj[4][3],
                                      bool full) {
    int hl = task / 14;
    int cg = task - hl * 14;
    int w0 = cg * 4;

    uint64_t vs[3], vz[3];
    int off;
    if (w0 == 0) {
        off = 0;
#pragma unroll
        for (int r = 0; r < 3; ++r) {
            int base = (hl + r) * ROWW;
            vs[r] = (((uint64_t)s_t[base] | ((uint64_t)s_t[base + 1] << 32)) << 4);
            vz[r] = (((uint64_t)z_t[base] | ((uint64_t)z_t[base + 1] << 32)) << 4);
        }
    } else {
        int st = 4 * w0 - 4;
        int i0 = st >> 5;
        off = st & 31;
#pragma unroll
        for (int r = 0; r < 3; ++r) {
            int base = (hl + r) * ROWW + i0;
            vs[r] = ((uint64_t)s_t[base] | ((uint64_t)s_t[base + 1] << 32));
            vz[r] = ((uint64_t)z_t[base] | ((uint64_t)z_t[base + 1] << 32));
        }
    }

    int res[4][4];
    if (full) {
#pragma unroll
        for (int k = 0; k < 4; ++k) {
            int sh = off + 4 * k;
            uint32_t s0 = (uint32_t)(vs[0] >> sh) & 0xFFFu;
            uint32_t s1 = (uint32_t)(vs[1] >> sh) & 0xFFFu;
            uint32_t s2 = (uint32_t)(vs[2] >> sh) & 0xFFFu;
            uint32_t z0 = (uint32_t)(vz[0] >> sh) & 0xFFFu;
            uint32_t z1 = (uint32_t)(vz[1] >> sh) & 0xFFFu;
            uint32_t z2 = (uint32_t)(vz[2] >> sh) & 0xFFFu;
            int vb = __popc(z0) + __popc(z1) + __popc(z2);
#pragma unroll
            for (int j = 0; j < 4; ++j) {
                int pc = __popc((s0 ^ wsj[j][0]) & z0)
                       + __popc((s1 ^ wsj[j][1]) & z1)
                       + __popc((s2 ^ wsj[j][2]) & z2);
                res[j][k] = vb - 2 * pc;
            }
        }
    } else {
#pragma unroll
        for (int k = 0; k < 4; ++k) {
            int sh = off + 4 * k;
            uint32_t s0 = (uint32_t)(vs[0] >> sh) & 0xFFFu;
            uint32_t s1 = (uint32_t)(vs[1] >> sh) & 0xFFFu;
            uint32_t s2 = (uint32_t)(vs[2] >> sh) & 0xFFFu;
            uint32_t z0 = (uint32_t)(vz[0] >> sh) & 0xFFFu;
            uint32_t z1 = (uint32_t)(vz[1] >> sh) & 0xFFFu;
            uint32_t z2 = (uint32_t)(vz[2] >> sh) & 0xFFFu;
#pragma unroll
            for (int j = 0; j < 4; ++j) {
                uint32_t m0 = z0 & wzj[j][0];
                uint32_t m1 = z1 & wzj[j][1];
                uint32_t m2 = z2 & wzj[j][2];
                int vb = __popc(m0) + __popc(m1) + __popc(m2);
                int pc = __popc((s0 ^ wsj[j][0]) & m0)
                       + __popc((s1 ^ wsj[j][1]) & m1)
                       + __popc((s2 ^ wsj[j][2]) & m2);
                res[j][k] = vb - 2 * pc;
            }
        }
    }

    // Epilogue: shuffled channel c' = j*64 + g; float4 shortcut + store.
    size_t pbase = (size_t)(half * 28 + hl) * W + w0;
    float4 sc[4];
#pragma unroll
    for (int j = 0; j < 4; ++j)
        sc[j] = *reinterpret_cast<const float4*>(Xn + (size_t)(j * 64 + g) * HW + pbase);
#pragma unroll
    for (int j = 0; j < 4; ++j) {
        size_t cofs = (size_t)(j * 64 + g) * HW + pbase;
        float4 o;
        o.x = add_rn((float)res[j][0], sc[j].x);
        o.y = add_rn((float)res[j][1], sc[j].y);
        o.z = add_rn((float)res[j][2], sc[j].z);
        o.w = add_rn((float)res[j][3], sc[j].w);
        *reinterpret_cast<float4*>(On + cofs) = o;
    }
}

__global__ __launch_bounds__(256, 6)
void binconv_kernel(const float* __restrict__ X,
                    const float* __restrict__ Wt,
                    const float* __restrict__ gamma,
                    const float* __restrict__ beta,
                    const float* __restrict__ mean,
                    const float* __restrict__ var,
                    float* __restrict__ out) {
    __shared__ uint32_t s_tile[2][TSZ];   // sign nibbles, double-buffered
    __shared__ uint32_t z_tile[2][TSZ];   // nonzero nibbles
    __shared__ uint32_t ws_l[4][3];       // weight sign rows (12-bit)
    __shared__ uint32_t wz_l[4][3];       // weight nz   rows (12-bit)

    const int bx  = blockIdx.x;
    const int n   = bx >> 6;
    const int g   = bx & 63;
    const int tid = threadIdx.x;

    // Zero both tile buffers (interiors are overwritten after the barriers).
    for (int i = tid; i < 2 * TSZ; i += 256) {
        (&s_tile[0][0])[i] = 0u;
        (&z_tile[0][0])[i] = 0u;
    }

    const float* Xn = X   + (size_t)n * IMG;
    float*       On = out + (size_t)n * IMG;

    // Half-0 staging loads issued first (input rows 0..28); latency hides
    // under the weight pack / BN-const setup below.
    Stage a0, a1;
    issueA(Xn, g, 0, tid, a0);
    if (tid < ATASKS - 256) issueA(Xn, g, 0, tid + 256, a1);

    // Threads 0..3 pack this group's 4 filters into 12-bit row patterns.
    // bit = kw*4 + ci  (kw aligns with window nibble: w-1, w, w+1).
    if (tid < 4) {
        const float* wc = Wt + (size_t)(g * 4 + tid) * 36;   // [ci][kh][kw]
        for (int r = 0; r < 3; ++r) {
            uint32_t s = 0, z = 0;
            for (int ci = 0; ci < 4; ++ci)
                for (int kw = 0; kw < 3; ++kw) {
                    float v = wc[ci * 9 + r * 3 + kw];
                    int b = kw * 4 + ci;
                    s |= (v > 0.f  ? 1u : 0u) << b;
                    z |= (v != 0.f ? 1u : 0u) << b;
                }
            ws_l[tid][r] = s; wz_l[tid][r] = z;
        }
    }

    // BN constants (strict np fp32 chain), block-uniform -> SGPRs.
    float inv[4], bias[4];
#pragma unroll
    for (int ci = 0; ci < 4; ++ci) {
        int c = g * 4 + ci;
        float s  = sqrtf(var[c] + EPS);   // correctly rounded
        float r  = 1.0f / s;              // correctly rounded
        float iv = mul_rn(gamma[c], r);
        inv[ci]  = rfl_f(iv);
        bias[ci] = rfl_f(sub_rn(beta[c], mul_rn(mean[c], iv)));
    }

    __syncthreads();                      // zeros + packed weights visible

    // Half-0 tile: input rows 0..28 -> tile rows 1..29 (row 0 = top pad).
    convA(a0, inv, bias, s_tile[0], z_tile[0], tid, 1);
    if (tid < ATASKS - 256) convA(a1, inv, bias, s_tile[0], z_tile[0], tid + 256, 1);

    // Weight masks to SGPRs (block-uniform).
    uint32_t wsj[4][3], wzj[4][3];
    bool full = true;
#pragma unroll
    for (int j = 0; j < 4; ++j)
#pragma unroll
        for (int r = 0; r < 3; ++r) {
            wsj[j][r] = __builtin_amdgcn_readfirstlane(ws_l[j][r]);
            wzj[j][r] = __builtin_amdgcn_readfirstlane(wz_l[j][r]);
            full = full && (wzj[j][r] == 0xFFFu);
        }

    __syncthreads();                      // tile 0 ready

    // --- Pipelined middle: half-1 loads overlapped with half-0 compute. ---
    // Half-1 stages input rows 27..55 -> tile rows 0..28 (row 29 = bottom
    // pad). sched_barrier(0) pins each load-issue above the covering compute
    // block so the compiler cannot sink it to its use (round-1 failure mode).
    issueA(Xn, g, 27, tid, a0);
    __builtin_amdgcn_sched_barrier(0);

    taskB(s_tile[0], z_tile[0], Xn, On, g, 0, tid, wsj, wzj, full);

    convA(a0, inv, bias, s_tile[1], z_tile[1], tid, 0);
    if (tid < ATASKS - 256) issueA(Xn, g, 27, tid + 256, a1);
    __builtin_amdgcn_sched_barrier(0);

    if (tid < BTASKS - 256)
        taskB(s_tile[0], z_tile[0], Xn, On, g, 0, tid + 256, wsj, wzj, full);

    if (tid < ATASKS - 256) convA(a1, inv, bias, s_tile[1], z_tile[1], tid + 256, 0);

    __syncthreads();                      // tile 1 ready

    taskB(s_tile[1], z_tile[1], Xn, On, g, 1, tid, wsj, wzj, full);
    if (tid < BTASKS - 256)
        taskB(s_tile[1], z_tile[1], Xn, On, g, 1, tid + 256, wsj, wzj, full);
}

// ---------------------------------------------------------------------------
extern "C" void kernel_launch(void* const* d_in, const int* in_sizes, int n_in,
                              void* d_out, int out_size, void* d_ws, size_t ws_size,
                              hipStream_t stream) {
    const float* X     = (const float*)d_in[0];
    const float* Wt    = (const float*)d_in[1];
    const float* gamma = (const float*)d_in[2];
    const float* beta  = (const float*)d_in[3];
    const float* mean  = (const float*)d_in[4];
    const float* var   = (const float*)d_in[5];
    float* out = (float*)d_out;

    int N = in_sizes[0] / IMG;        // 32

    // grid: n (32) x group (64) = 2048 blocks
    binconv_kernel<<<N * 64, 256, 0, stream>>>(X, Wt, gamma, beta, mean, var, out);
}

// Round 4
// 201.501 us; speedup vs baseline: 1.0962x; 1.0472x over previous
//
#include <hip/hip_runtime.h>
#include <stdint.h>

// Problem constants (fixed by the reference)
#define H 56
#define W 56
#define HW (H * W)          // 3136
#define CIN 256
#define IMG (CIN * HW)      // 802816 elements per image
#define EPS 1e-5f

#define ROWW 8              // u32 words per tile row: 32B = 64 nibbles
#define TR2 30              // tile rows: 28 outputs + 2 halo/padding
#define TSZ (TR2 * ROWW)    // 240 words per tile
#define ATASKS 406          // 29 staged input rows x 14 col-groups
#define BTASKS 392          // 28 output rows x 14 col-groups

// Strict fp32 RN ops, immune to -ffp-contract (inline asm cannot be fused).
// The np reference's exact-zero BN outputs (sign->0) only reproduce with the
// two-rounding chain round(round(x*inv)+bias).
__device__ __forceinline__ float mul_rn(float a, float b) {
    float d; asm("v_mul_f32 %0, %1, %2" : "=v"(d) : "v"(a), "v"(b)); return d;
}
__device__ __forceinline__ float add_rn(float a, float b) {
    float d; asm("v_add_f32 %0, %1, %2" : "=v"(d) : "v"(a), "v"(b)); return d;
}
__device__ __forceinline__ float sub_rn(float a, float b) {
    float d; asm("v_sub_f32 %0, %1, %2" : "=v"(d) : "v"(a), "v"(b)); return d;
}
// Scalar-operand variants: BN constants are block-uniform -> SGPR (src0 may be
// scalar). Multiplication/addition commute bit-exactly in RN.
__device__ __forceinline__ float mul_rn_sv(float s, float v) {
    float d; asm("v_mul_f32 %0, %1, %2" : "=v"(d) : "s"(s), "v"(v)); return d;
}
__device__ __forceinline__ float add_rn_sv(float s, float v) {
    float d; asm("v_add_f32 %0, %1, %2" : "=v"(d) : "s"(s), "v"(v)); return d;
}
__device__ __forceinline__ float rfl_f(float x) {
    return __int_as_float(__builtin_amdgcn_readfirstlane(__float_as_int(x)));
}

// ---------------------------------------------------------------------------
// Fused: BN -> ternary sign -> XNOR-popcount grouped 3x3 conv -> shuffle -> +x
//
// Round-4 design: NO register prefetch, NO pairing (rounds 2/3 proved the
// in-flight Stage batches spill: VGPR collapse + ~50-115 MB scratch traffic).
// Instead: smallest clean block = (n, g, row-half), single 1.9 KB LDS tile,
// two barriers — and a 4096-block grid (16 queued per CU). Latency hiding is
// inter-block: ~8 resident blocks/CU at ~60 VGPRs overlap each other's
// memory phases, and the replacement queue removes the straggler tail that
// capped rounds 0/1/3 at 34-45% occupancy.
//
// LDS tile: 30 rows x 8 u32 of packed 4-bit nibbles (nibble w = 4 channel
// bits of pixel w). half0 stages input rows 0..28 at tile rows 1..29 (row 0
// = top pad); half1 stages rows 27..55 at tile rows 0..28 (row 29 = bottom
// pad). Unwritten pad rows and nibble cols 56..63 stay zero => z-plane zeros
// subsume all geometric padding.
// ---------------------------------------------------------------------------

__global__ __launch_bounds__(256)
void binconv_kernel(const float* __restrict__ X,
                    const float* __restrict__ Wt,
                    const float* __restrict__ gamma,
                    const float* __restrict__ beta,
                    const float* __restrict__ mean,
                    const float* __restrict__ var,
                    float* __restrict__ out) {
    __shared__ uint32_t s_tile[TSZ];      // sign nibbles
    __shared__ uint32_t z_tile[TSZ];      // nonzero nibbles
    __shared__ uint32_t ws_l[4][3];       // weight sign rows (12-bit)
    __shared__ uint32_t wz_l[4][3];       // weight nz   rows (12-bit)

    const int bx   = blockIdx.x;
    const int half = bx & 1;
    const int g    = (bx >> 1) & 63;
    const int n    = bx >> 7;
    const int tid  = threadIdx.x;

    // Zero the tile (interior rows are overwritten before the second barrier).
    for (int i = tid; i < 2 * TSZ; i += 256) {
        if (i < TSZ) s_tile[i] = 0u;
        else         z_tile[i - TSZ] = 0u;
    }

    // Threads 0..3 pack this group's 4 filters into 12-bit row patterns.
    // bit = kw*4 + ci  (kw aligns with window nibble: w-1, w, w+1).
    if (tid < 4) {
        const float* wc = Wt + (size_t)(g * 4 + tid) * 36;   // [ci][kh][kw]
        for (int r = 0; r < 3; ++r) {
            uint32_t s = 0, z = 0;
            for (int ci = 0; ci < 4; ++ci)
                for (int kw = 0; kw < 3; ++kw) {
                    float v = wc[ci * 9 + r * 3 + kw];
                    int b = kw * 4 + ci;
                    s |= (v > 0.f  ? 1u : 0u) << b;
                    z |= (v != 0.f ? 1u : 0u) << b;
                }
            ws_l[tid][r] = s; wz_l[tid][r] = z;
        }
    }

    // BN constants (strict np fp32 chain), block-uniform -> SGPRs.
    float inv[4], bias[4];
#pragma unroll
    for (int ci = 0; ci < 4; ++ci) {
        int c = g * 4 + ci;
        float s  = sqrtf(var[c] + EPS);   // correctly rounded
        float r  = 1.0f / s;              // correctly rounded
        float iv = mul_rn(gamma[c], r);
        inv[ci]  = rfl_f(iv);
        bias[ci] = rfl_f(sub_rn(beta[c], mul_rn(mean[c], iv)));
    }

    const float* Xn = X   + (size_t)n * IMG;
    float*       On = out + (size_t)n * IMG;

    __syncthreads();                      // zeros + packed weights visible

    // Phase A: stage 29 input rows (rowbase..rowbase+28) as sign/nz nibbles.
    const int rowbase = half * 27;        // half0: rows 0..28, half1: 27..55
    const int rtoff   = 1 - half;         // tile row = ar + rtoff
    for (int task = tid; task < ATASKS; task += 256) {
        int ar = task / 14;
        int cg = task - ar * 14;
        int off = (rowbase + ar) * W + cg * 4;
        uint32_t s16 = 0, z16 = 0;
#pragma unroll
        for (int ci = 0; ci < 4; ++ci) {
            const float4 v = *reinterpret_cast<const float4*>(
                Xn + (size_t)(g * 4 + ci) * HW + off);
            float t0 = add_rn_sv(bias[ci], mul_rn_sv(inv[ci], v.x));
            float t1 = add_rn_sv(bias[ci], mul_rn_sv(inv[ci], v.y));
            float t2 = add_rn_sv(bias[ci], mul_rn_sv(inv[ci], v.z));
            float t3 = add_rn_sv(bias[ci], mul_rn_sv(inv[ci], v.w));
            s16 |= ((t0 > 0.f ? 1u : 0u) << ci)        | ((t1 > 0.f ? 1u : 0u) << (4 + ci))
                 | ((t2 > 0.f ? 1u : 0u) << (8 + ci))  | ((t3 > 0.f ? 1u : 0u) << (12 + ci));
            z16 |= ((t0 != 0.f ? 1u : 0u) << ci)       | ((t1 != 0.f ? 1u : 0u) << (4 + ci))
                 | ((t2 != 0.f ? 1u : 0u) << (8 + ci)) | ((t3 != 0.f ? 1u : 0u) << (12 + ci));
        }
        int rt = ar + rtoff;
        reinterpret_cast<uint16_t*>(&s_tile[rt * ROWW])[cg] = (uint16_t)s16;
        reinterpret_cast<uint16_t*>(&z_tile[rt * ROWW])[cg] = (uint16_t)z16;
    }

    // Weight masks to SGPRs (block-uniform).
    uint32_t wsj[4][3], wzj[4][3];
    bool full = true;
#pragma unroll
    for (int j = 0; j < 4; ++j)
#pragma unroll
        for (int r = 0; r < 3; ++r) {
            wsj[j][r] = __builtin_amdgcn_readfirstlane(ws_l[j][r]);
            wzj[j][r] = __builtin_amdgcn_readfirstlane(wz_l[j][r]);
            full = full && (wzj[j][r] == 0xFFFu);
        }

    __syncthreads();                      // tile ready

    // Phase B: per task = (output row, 4-px group): 6 two-dword LDS reads,
    // XNOR-popcount for 4 filters x 4 px, shuffled float4 shortcut + store.
    for (int task = tid; task < BTASKS; task += 256) {
        int hl = task / 14;
        int cg = task - hl * 14;
        int w0 = cg * 4;
        size_t pbase = (size_t)(half * 28 + hl) * W + w0;

        uint64_t vs[3], vz[3];
        int off;
        if (w0 == 0) {
            off = 0;
#pragma unroll
            for (int r = 0; r < 3; ++r) {
                int base = (hl + r) * ROWW;
                vs[r] = (((uint64_t)s_tile[base] | ((uint64_t)s_tile[base + 1] << 32)) << 4);
                vz[r] = (((uint64_t)z_tile[base] | ((uint64_t)z_tile[base + 1] << 32)) << 4);
            }
        } else {
            int st = 4 * w0 - 4;
            int i0 = st >> 5;
            off = st & 31;
#pragma unroll
            for (int r = 0; r < 3; ++r) {
                int base = (hl + r) * ROWW + i0;
                vs[r] = ((uint64_t)s_tile[base] | ((uint64_t)s_tile[base + 1] << 32));
                vz[r] = ((uint64_t)z_tile[base] | ((uint64_t)z_tile[base + 1] << 32));
            }
        }

        // Shortcut loads issued before the popcount block: ~250 VALU ops of
        // cover; sc[4]=16 regs keeps peak pressure inside the ~60-reg budget.
        float4 sc[4];
#pragma unroll
        for (int j = 0; j < 4; ++j)
            sc[j] = *reinterpret_cast<const float4*>(Xn + (size_t)(j * 64 + g) * HW + pbase);

        int res[4][4];
        if (full) {
#pragma unroll
            for (int k = 0; k < 4; ++k) {
                int sh = off + 4 * k;
                uint32_t s0 = (uint32_t)(vs[0] >> sh) & 0xFFFu;
                uint32_t s1 = (uint32_t)(vs[1] >> sh) & 0xFFFu;
                uint32_t s2 = (uint32_t)(vs[2] >> sh) & 0xFFFu;
                uint32_t z0 = (uint32_t)(vz[0] >> sh) & 0xFFFu;
                uint32_t z1 = (uint32_t)(vz[1] >> sh) & 0xFFFu;
                uint32_t z2 = (uint32_t)(vz[2] >> sh) & 0xFFFu;
                int vb = __popc(z0) + __popc(z1) + __popc(z2);
#pragma unroll
                for (int j = 0; j < 4; ++j) {
                    int pc = __popc((s0 ^ wsj[j][0]) & z0)
                           + __popc((s1 ^ wsj[j][1]) & z1)
                           + __popc((s2 ^ wsj[j][2]) & z2);
                    res[j][k] = vb - 2 * pc;
                }
            }
        } else {
#pragma unroll
            for (int k = 0; k < 4; ++k) {
                int sh = off + 4 * k;
                uint32_t s0 = (uint32_t)(vs[0] >> sh) & 0xFFFu;
                uint32_t s1 = (uint32_t)(vs[1] >> sh) & 0xFFFu;
                uint32_t s2 = (uint32_t)(vs[2] >> sh) & 0xFFFu;
                uint32_t z0 = (uint32_t)(vz[0] >> sh) & 0xFFFu;
                uint32_t z1 = (uint32_t)(vz[1] >> sh) & 0xFFFu;
                uint32_t z2 = (uint32_t)(vz[2] >> sh) & 0xFFFu;
#pragma unroll
                for (int j = 0; j < 4; ++j) {
                    uint32_t m0 = z0 & wzj[j][0];
                    uint32_t m1 = z1 & wzj[j][1];
                    uint32_t m2 = z2 & wzj[j][2];
                    int vb = __popc(m0) + __popc(m1) + __popc(m2);
                    int pc = __popc((s0 ^ wsj[j][0]) & m0)
                           + __popc((s1 ^ wsj[j][1]) & m1)
                           + __popc((s2 ^ wsj[j][2]) & m2);
                    res[j][k] = vb - 2 * pc;
                }
            }
        }

        // Epilogue: shuffled channel c' = j*64 + g; float4 shortcut + store.
#pragma unroll
        for (int j = 0; j < 4; ++j) {
            size_t cofs = (size_t)(j * 64 + g) * HW + pbase;
            float4 o;
            o.x = add_rn((float)res[j][0], sc[j].x);
            o.y = add_rn((float)res[j][1], sc[j].y);
            o.z = add_rn((float)res[j][2], sc[j].z);
            o.w = add_rn((float)res[j][3], sc[j].w);
            *reinterpret_cast<float4*>(On + cofs) = o;
        }
    }
}

// ---------------------------------------------------------------------------
extern "C" void kernel_launch(void* const* d_in, const int* in_sizes, int n_in,
                              void* d_out, int out_size, void* d_ws, size_t ws_size,
                              hipStream_t stream) {
    const float* X     = (const float*)d_in[0];
    const float* Wt    = (const float*)d_in[1];
    const float* gamma = (const float*)d_in[2];
    const float* beta  = (const float*)d_in[3];
    const float* mean  = (const float*)d_in[4];
    const float* var   = (const float*)d_in[5];
    float* out = (float*)d_out;

    int N = in_sizes[0] / IMG;        // 32

    // grid: n (32) x group (64) x row-half (2) = 4096 blocks = 16 queued/CU
    binconv_kernel<<<N * 64 * 2, 256, 0, stream>>>(X, Wt, gamma, beta, mean, var, out);
}

// Round 5
// 200.597 us; speedup vs baseline: 1.1011x; 1.0045x over previous
//
#include <hip/hip_runtime.h>
#include <stdint.h>

// Problem constants (fixed by the reference)
#define H 56
#define W 56
#define HW (H * W)          // 3136
#define CIN 256
#define IMG (CIN * HW)      // 802816 elements per image
#define EPS 1e-5f

#define ROWW 8              // u32 words per tile row: 32B = 64 nibbles
#define TR2 30              // tile rows: 28 outputs + 2 halo/padding
#define TSZ (TR2 * ROWW)    // 240 words per tile
#define ATASKS 406          // 29 staged input rows x 14 col-groups
#define BTASKS 392          // 28 output rows x 14 col-groups
#define NT 384              // 6 waves: ~1 task/thread in both phases

// Strict fp32 RN ops, immune to -ffp-contract (inline asm cannot be fused).
// The np reference's exact-zero BN outputs (sign->0) only reproduce with the
// two-rounding chain round(round(x*inv)+bias).
__device__ __forceinline__ float mul_rn(float a, float b) {
    float d; asm("v_mul_f32 %0, %1, %2" : "=v"(d) : "v"(a), "v"(b)); return d;
}
__device__ __forceinline__ float add_rn(float a, float b) {
    float d; asm("v_add_f32 %0, %1, %2" : "=v"(d) : "v"(a), "v"(b)); return d;
}
__device__ __forceinline__ float sub_rn(float a, float b) {
    float d; asm("v_sub_f32 %0, %1, %2" : "=v"(d) : "v"(a), "v"(b)); return d;
}
// Scalar-operand variants: BN constants are block-uniform -> SGPR (src0 may be
// scalar). Multiplication/addition commute bit-exactly in RN.
__device__ __forceinline__ float mul_rn_sv(float s, float v) {
    float d; asm("v_mul_f32 %0, %1, %2" : "=v"(d) : "s"(s), "v"(v)); return d;
}
__device__ __forceinline__ float add_rn_sv(float s, float v) {
    float d; asm("v_add_f32 %0, %1, %2" : "=v"(d) : "s"(s), "v"(v)); return d;
}
__device__ __forceinline__ float rfl_f(float x) {
    return __int_as_float(__builtin_amdgcn_readfirstlane(__float_as_int(x)));
}

// ---------------------------------------------------------------------------
// Fused: BN -> ternary sign -> XNOR-popcount grouped 3x3 conv -> shuffle -> +x
//
// Round-5 design: block = (n, g, row-half) with 384 threads (6 waves).
//  * ~1 task/thread in BOTH phases (A: 406/384, B: 392/384) -> the round-4
//    wave imbalance (1.53 tasks/thread, second pass at <53% lane util) is
//    gone; block exit no longer gated by a straggler wave.
//  * 5 blocks/CU = 30/32 waves static occupancy; __launch_bounds__(384,8)
//    pins VGPR<=64 (working set ~55, fits -- rounds 2/3 spilled only because
//    they held multi-stage prefetches).
//  * Task-0 loads + BN-param loads issued at kernel top, packed to 2 regs
//    pre-barrier; only the u16 LDS writes happen post-barrier.
//  * Phase B: LDS reads issued, then shortcut loads, then extraction ->
//    popcount covers both latencies.
//  * XCD swizzle: all 128 blocks of plane n -> XCD n&7 (bx%8 round-robin),
//    so one 3.2 MB X-plane lives in one 4 MiB XCD L2; shuffle/shortcut
//    re-reads hit L2 instead of L3. Bijective -> correctness-neutral.
//
// LDS tile: 30 rows x 8 u32 of packed 4-bit nibbles (nibble w = 4 channel
// bits of pixel w). half0 stages input rows 0..28 at tile rows 1..29 (row 0
// = top pad); half1 stages rows 27..55 at tile rows 0..28 (row 29 = bottom
// pad). Unwritten pad rows and nibble cols 56..63 stay zero => z-plane zeros
// subsume all geometric padding.
// ---------------------------------------------------------------------------

__global__ __launch_bounds__(NT, 8)
void binconv_kernel(const float* __restrict__ X,
                    const float* __restrict__ Wt,
                    const float* __restrict__ gamma,
                    const float* __restrict__ beta,
                    const float* __restrict__ mean,
                    const float* __restrict__ var,
                    float* __restrict__ out) {
    __shared__ uint32_t s_tile[TSZ];      // sign nibbles
    __shared__ uint32_t z_tile[TSZ];      // nonzero nibbles
    __shared__ uint32_t ws_l[4][3];       // weight sign rows (12-bit)
    __shared__ uint32_t wz_l[4][3];       // weight nz   rows (12-bit)

    // XCD-swizzled decode: bx = (n>>3)<<10 | (g*2+half)<<3 | (n&7).
    const int bx   = blockIdx.x;
    const int n    = ((bx >> 10) << 3) | (bx & 7);
    const int rem  = (bx >> 3) & 127;
    const int g    = rem >> 1;
    const int half = rem & 1;
    const int tid  = threadIdx.x;

    const int rowbase = half * 27;        // half0: rows 0..28, half1: 27..55
    const int rtoff   = 1 - half;         // tile row = ar + rtoff

    const float* Xn = X   + (size_t)n * IMG;
    float*       On = out + (size_t)n * IMG;

    // --- 1. Issue task-0 staging loads immediately (before any LDS work). ---
    const int ar0 = tid / 14;
    const int cg0 = tid - ar0 * 14;
    const float* p0 = Xn + (size_t)(g * 4) * HW + (rowbase + ar0) * W + cg0 * 4;
    float4 q0[4];
#pragma unroll
    for (int ci = 0; ci < 4; ++ci)
        q0[ci] = *reinterpret_cast<const float4*>(p0 + (size_t)ci * HW);

    // --- 2. BN parameter loads (vectorized; block-uniform addresses). ---
    const float4 vv = *reinterpret_cast<const float4*>(var   + g * 4);
    const float4 vg = *reinterpret_cast<const float4*>(gamma + g * 4);
    const float4 vb = *reinterpret_cast<const float4*>(beta  + g * 4);
    const float4 vm = *reinterpret_cast<const float4*>(mean  + g * 4);

    // --- 3. Zero the tile (covers pad rows / word 7; interior overwritten). --
    for (int i = tid; i < 2 * TSZ; i += NT) {
        if (i < TSZ) s_tile[i] = 0u;
        else         z_tile[i - TSZ] = 0u;
    }

    // --- 4. Weight pack, spread over 12 threads (filter j, row r each). ---
    // bit = kw*4 + ci  (kw aligns with window nibble: w-1, w, w+1).
    if (tid < 12) {
        int j = tid / 3, r = tid - j * 3;
        const float* wc = Wt + (size_t)(g * 4 + j) * 36 + r * 3;  // [ci][kh][kw]
        uint32_t s = 0, z = 0;
        for (int ci = 0; ci < 4; ++ci)
            for (int kw = 0; kw < 3; ++kw) {
                float v = wc[ci * 9 + kw];
                int b = kw * 4 + ci;
                s |= (v > 0.f  ? 1u : 0u) << b;
                z |= (v != 0.f ? 1u : 0u) << b;
            }
        ws_l[j][r] = s; wz_l[j][r] = z;
    }

    // --- 5. BN constants (strict np fp32 chain), block-uniform -> SGPRs. ---
    float inv[4], bias[4];
    {
        const float va[4] = {vv.x, vv.y, vv.z, vv.w};
        const float ga[4] = {vg.x, vg.y, vg.z, vg.w};
        const float ba[4] = {vb.x, vb.y, vb.z, vb.w};
        const float ma[4] = {vm.x, vm.y, vm.z, vm.w};
#pragma unroll
        for (int ci = 0; ci < 4; ++ci) {
            float s  = sqrtf(va[ci] + EPS);   // correctly rounded
            float r  = 1.0f / s;              // correctly rounded
            float iv = mul_rn(ga[ci], r);
            inv[ci]  = rfl_f(iv);
            bias[ci] = rfl_f(sub_rn(ba[ci], mul_rn(ma[ci], iv)));
        }
    }

    // --- 6. Pack task 0 pre-barrier (frees the 16 staging regs). ---
    uint32_t s16_0 = 0, z16_0 = 0;
#pragma unroll
    for (int ci = 0; ci < 4; ++ci) {
        float t0 = add_rn_sv(bias[ci], mul_rn_sv(inv[ci], q0[ci].x));
        float t1 = add_rn_sv(bias[ci], mul_rn_sv(inv[ci], q0[ci].y));
        float t2 = add_rn_sv(bias[ci], mul_rn_sv(inv[ci], q0[ci].z));
        float t3 = add_rn_sv(bias[ci], mul_rn_sv(inv[ci], q0[ci].w));
        s16_0 |= ((t0 > 0.f ? 1u : 0u) << ci)        | ((t1 > 0.f ? 1u : 0u) << (4 + ci))
               | ((t2 > 0.f ? 1u : 0u) << (8 + ci))  | ((t3 > 0.f ? 1u : 0u) << (12 + ci));
        z16_0 |= ((t0 != 0.f ? 1u : 0u) << ci)       | ((t1 != 0.f ? 1u : 0u) << (4 + ci))
               | ((t2 != 0.f ? 1u : 0u) << (8 + ci)) | ((t3 != 0.f ? 1u : 0u) << (12 + ci));
    }

    __syncthreads();                      // zeros + packed weights visible

    // --- 7. Write task 0; inline the 22 remainder tasks (wave 0 only). ---
    {
        int rt = ar0 + rtoff;
        reinterpret_cast<uint16_t*>(&s_tile[rt * ROWW])[cg0] = (uint16_t)s16_0;
        reinterpret_cast<uint16_t*>(&z_tile[rt * ROWW])[cg0] = (uint16_t)z16_0;
    }
    for (int t = tid + NT; t < ATASKS; t += NT) {
        int ar = t / 14;
        int cg = t - ar * 14;
        const float* p = Xn + (size_t)(g * 4) * HW + (rowbase + ar) * W + cg * 4;
        uint32_t s16 = 0, z16 = 0;
#pragma unroll
        for (int ci = 0; ci < 4; ++ci) {
            const float4 v = *reinterpret_cast<const float4*>(p + (size_t)ci * HW);
            float t0 = add_rn_sv(bias[ci], mul_rn_sv(inv[ci], v.x));
            float t1 = add_rn_sv(bias[ci], mul_rn_sv(inv[ci], v.y));
            float t2 = add_rn_sv(bias[ci], mul_rn_sv(inv[ci], v.z));
            float t3 = add_rn_sv(bias[ci], mul_rn_sv(inv[ci], v.w));
            s16 |= ((t0 > 0.f ? 1u : 0u) << ci)        | ((t1 > 0.f ? 1u : 0u) << (4 + ci))
                 | ((t2 > 0.f ? 1u : 0u) << (8 + ci))  | ((t3 > 0.f ? 1u : 0u) << (12 + ci));
            z16 |= ((t0 != 0.f ? 1u : 0u) << ci)       | ((t1 != 0.f ? 1u : 0u) << (4 + ci))
                 | ((t2 != 0.f ? 1u : 0u) << (8 + ci)) | ((t3 != 0.f ? 1u : 0u) << (12 + ci));
        }
        int rt = ar + rtoff;
        reinterpret_cast<uint16_t*>(&s_tile[rt * ROWW])[cg] = (uint16_t)s16;
        reinterpret_cast<uint16_t*>(&z_tile[rt * ROWW])[cg] = (uint16_t)z16;
    }

    // Weight masks to SGPRs (block-uniform; LDS was written pre-barrier).
    uint32_t wsj[4][3], wzj[4][3];
    bool full = true;
#pragma unroll
    for (int j = 0; j < 4; ++j)
#pragma unroll
        for (int r = 0; r < 3; ++r) {
            wsj[j][r] = __builtin_amdgcn_readfirstlane(ws_l[j][r]);
            wzj[j][r] = __builtin_amdgcn_readfirstlane(wz_l[j][r]);
            full = full && (wzj[j][r] == 0xFFFu);
        }

    __syncthreads();                      // tile ready

    // --- Phase B: ~1 task/thread (8 threads take a second). ---
    for (int task = tid; task < BTASKS; task += NT) {
        int hl = task / 14;
        int cg = task - hl * 14;
        int w0 = cg * 4;
        size_t pbase = (size_t)(half * 28 + hl) * W + w0;

        // LDS reads issued first...
        uint64_t vs[3], vz[3];
        int off;
        if (w0 == 0) {
            off = 0;
#pragma unroll
            for (int r = 0; r < 3; ++r) {
                int base = (hl + r) * ROWW;
                vs[r] = (((uint64_t)s_tile[base] | ((uint64_t)s_tile[base + 1] << 32)) << 4);
                vz[r] = (((uint64_t)z_tile[base] | ((uint64_t)z_tile[base + 1] << 32)) << 4);
            }
        } else {
            int st = 4 * w0 - 4;
            int i0 = st >> 5;
            off = st & 31;
#pragma unroll
            for (int r = 0; r < 3; ++r) {
                int base = (hl + r) * ROWW + i0;
                vs[r] = ((uint64_t)s_tile[base] | ((uint64_t)s_tile[base + 1] << 32));
                vz[r] = ((uint64_t)z_tile[base] | ((uint64_t)z_tile[base + 1] << 32));
            }
        }

        // ...then shortcut loads (mostly L2 hits after XCD swizzle); the
        // popcount block below covers both latencies.
        float4 sc[4];
#pragma unroll
        for (int j = 0; j < 4; ++j)
            sc[j] = *reinterpret_cast<const float4*>(Xn + (size_t)(j * 64 + g) * HW + pbase);

        int res[4][4];
        if (full) {
#pragma unroll
            for (int k = 0; k < 4; ++k) {
                int sh = off + 4 * k;
                uint32_t s0 = (uint32_t)(vs[0] >> sh) & 0xFFFu;
                uint32_t s1 = (uint32_t)(vs[1] >> sh) & 0xFFFu;
                uint32_t s2 = (uint32_t)(vs[2] >> sh) & 0xFFFu;
                uint32_t z0 = (uint32_t)(vz[0] >> sh) & 0xFFFu;
                uint32_t z1 = (uint32_t)(vz[1] >> sh) & 0xFFFu;
                uint32_t z2 = (uint32_t)(vz[2] >> sh) & 0xFFFu;
                int vb = __popc(z0) + __popc(z1) + __popc(z2);
#pragma unroll
                for (int j = 0; j < 4; ++j) {
                    int pc = __popc((s0 ^ wsj[j][0]) & z0)
                           + __popc((s1 ^ wsj[j][1]) & z1)
                           + __popc((s2 ^ wsj[j][2]) & z2);
                    res[j][k] = vb - 2 * pc;
                }
            }
        } else {
#pragma unroll
            for (int k = 0; k < 4; ++k) {
                int sh = off + 4 * k;
                uint32_t s0 = (uint32_t)(vs[0] >> sh) & 0xFFFu;
                uint32_t s1 = (uint32_t)(vs[1] >> sh) & 0xFFFu;
                uint32_t s2 = (uint32_t)(vs[2] >> sh) & 0xFFFu;
                uint32_t z0 = (uint32_t)(vz[0] >> sh) & 0xFFFu;
                uint32_t z1 = (uint32_t)(vz[1] >> sh) & 0xFFFu;
                uint32_t z2 = (uint32_t)(vz[2] >> sh) & 0xFFFu;
#pragma unroll
                for (int j = 0; j < 4; ++j) {
                    uint32_t m0 = z0 & wzj[j][0];
                    uint32_t m1 = z1 & wzj[j][1];
                    uint32_t m2 = z2 & wzj[j][2];
                    int vb = __popc(m0) + __popc(m1) + __popc(m2);
                    int pc = __popc((s0 ^ wsj[j][0]) & m0)
                           + __popc((s1 ^ wsj[j][1]) & m1)
                           + __popc((s2 ^ wsj[j][2]) & m2);
                    res[j][k] = vb - 2 * pc;
                }
            }
        }

        // Epilogue: shuffled channel c' = j*64 + g; float4 shortcut + store.
#pragma unroll
        for (int j = 0; j < 4; ++j) {
            size_t cofs = (size_t)(j * 64 + g) * HW + pbase;
            float4 o;
            o.x = add_rn((float)res[j][0], sc[j].x);
            o.y = add_rn((float)res[j][1], sc[j].y);
            o.z = add_rn((float)res[j][2], sc[j].z);
            o.w = add_rn((float)res[j][3], sc[j].w);
            *reinterpret_cast<float4*>(On + cofs) = o;
        }
    }
}

// ---------------------------------------------------------------------------
extern "C" void kernel_launch(void* const* d_in, const int* in_sizes, int n_in,
                              void* d_out, int out_size, void* d_ws, size_t ws_size,
                              hipStream_t stream) {
    const float* X     = (const float*)d_in[0];
    const float* Wt    = (const float*)d_in[1];
    const float* gamma = (const float*)d_in[2];
    const float* beta  = (const float*)d_in[3];
    const float* mean  = (const float*)d_in[4];
    const float* var   = (const float*)d_in[5];
    float* out = (float*)d_out;

    int N = in_sizes[0] / IMG;        // 32

    // grid: n (32) x group (64) x row-half (2) = 4096 blocks, XCD-swizzled
    binconv_kernel<<<N * 64 * 2, NT, 0, stream>>>(X, Wt, gamma, beta, mean, var, out);
}

// Round 7
// 197.411 us; speedup vs baseline: 1.1189x; 1.0161x over previous
//
#include <hip/hip_runtime.h>
#include <stdint.h>

// Problem constants (fixed by the reference)
#define H 56
#define W 56
#define HW (H * W)          // 3136
#define CIN 256
#define IMG (CIN * HW)      // 802816 elements per image
#define EPS 1e-5f

#define ROWW 8              // u32 words per tile row: 32B = 64 nibbles
#define TR2 30              // tile rows: 28 outputs + 2 halo/padding
#define TSZ (TR2 * ROWW)    // 240 words per tile
#define ATASKS 406          // 29 staged input rows x 14 col-groups
#define BTASKS 392          // 28 output rows x 14 col-groups

// Strict fp32 RN ops, immune to -ffp-contract (inline asm cannot be fused).
// The np reference's exact-zero BN outputs (sign->0) only reproduce with the
// two-rounding chain round(round(x*inv)+bias).
__device__ __forceinline__ float mul_rn(float a, float b) {
    float d; asm("v_mul_f32 %0, %1, %2" : "=v"(d) : "v"(a), "v"(b)); return d;
}
__device__ __forceinline__ float add_rn(float a, float b) {
    float d; asm("v_add_f32 %0, %1, %2" : "=v"(d) : "v"(a), "v"(b)); return d;
}
__device__ __forceinline__ float sub_rn(float a, float b) {
    float d; asm("v_sub_f32 %0, %1, %2" : "=v"(d) : "v"(a), "v"(b)); return d;
}
// Scalar-operand variants: BN constants are block-uniform -> SGPR (src0 may be
// scalar). Multiplication/addition commute bit-exactly in RN.
__device__ __forceinline__ float mul_rn_sv(float s, float v) {
    float d; asm("v_mul_f32 %0, %1, %2" : "=v"(d) : "s"(s), "v"(v)); return d;
}
__device__ __forceinline__ float add_rn_sv(float s, float v) {
    float d; asm("v_add_f32 %0, %1, %2" : "=v"(d) : "s"(s), "v"(v)); return d;
}
__device__ __forceinline__ float rfl_f(float x) {
    return __int_as_float(__builtin_amdgcn_readfirstlane(__float_as_int(x)));
}

// ---------------------------------------------------------------------------
// Fused: BN -> ternary sign -> XNOR-popcount grouped 3x3 conv -> shuffle -> +x
//
// Round-7 = round-6 with the race fixed: the weight-mask SGPR hoist now reads
// ws_l/wz_l AFTER the single barrier. (R6 read them pre-barrier, but only
// wave 0 writes them -> waves 1-3 read garbage; absmax=32.)
//
// Structure:
//  * 256 threads, NATURAL register allocation (every forced launch_bounds
//    min-waves cap spilled in rounds 2/3/5: VGPR collapse + scratch traffic).
//  * XCD swizzle: all 128 blocks of plane n land on XCD n&7, so one 3.2 MB
//    X-plane lives in that XCD's 4 MiB L2; the shuffled shortcut re-read hits
//    cache instead of HBM (R5: FETCH 100->82 MB even with spill pollution).
//  * Single-barrier: only the pad row + word 7 of each row need zeroing
//    (disjoint from phase-A's u16 writes to words 0..6) => no ordering
//    barrier needed before phase A. Block runs loads/BN/pack from cycle 0,
//    one __syncthreads(), phase B.
//
// LDS tile: 30 rows x 8 u32 of packed 4-bit nibbles (nibble w = 4 channel
// bits of pixel w). half0 stages input rows 0..28 at tile rows 1..29 (row 0
// = top pad); half1 stages rows 27..55 at tile rows 0..28 (row 29 = bottom
// pad). Pad row + word 7 (nibbles 56..63) are zero => z-plane zeros subsume
// all geometric padding.
// ---------------------------------------------------------------------------

__global__ __launch_bounds__(256)
void binconv_kernel(const float* __restrict__ X,
                    const float* __restrict__ Wt,
                    const float* __restrict__ gamma,
                    const float* __restrict__ beta,
                    const float* __restrict__ mean,
                    const float* __restrict__ var,
                    float* __restrict__ out) {
    __shared__ uint32_t s_tile[TSZ];      // sign nibbles
    __shared__ uint32_t z_tile[TSZ];      // nonzero nibbles
    __shared__ uint32_t ws_l[4][3];       // weight sign rows (12-bit)
    __shared__ uint32_t wz_l[4][3];       // weight nz   rows (12-bit)

    // XCD-swizzled decode: bx = (n>>3)<<10 | (g*2+half)<<3 | (n&7).
    // Dispatch round-robins blocks over XCDs by bx, so bx%8 pins the XCD.
    const int bx   = blockIdx.x;
    const int n    = ((bx >> 10) << 3) | (bx & 7);
    const int rem  = (bx >> 3) & 127;
    const int g    = rem >> 1;
    const int half = rem & 1;
    const int tid  = threadIdx.x;

    const int rowbase = half * 27;        // half0: rows 0..28, half1: 27..55
    const int rtoff   = 1 - half;         // tile row = ar + rtoff
    const int padrow  = half * 29;        // unwritten tile row (0 or 29)

    const float* Xn = X   + (size_t)n * IMG;
    float*       On = out + (size_t)n * IMG;

    // --- Targeted zeroing: ONLY the bytes phase A never writes. ---
    // tasks 0..29: word 7 of tile row t   (both planes)
    // tasks 30..36: words 0..6 of pad row (both planes)
    if (tid < 37) {
        int idx = (tid < 30) ? (tid * ROWW + 7) : (padrow * ROWW + (tid - 30));
        s_tile[idx] = 0u;
        z_tile[idx] = 0u;
    }

    // --- Weight pack, spread over 12 threads (filter j, row r each). ---
    // bit = kw*4 + ci  (kw aligns with window nibble: w-1, w, w+1).
    if (tid < 12) {
        int j = tid / 3, r = tid - j * 3;
        const float* wc = Wt + (size_t)(g * 4 + j) * 36 + r * 3;  // [ci][kh][kw]
        uint32_t s = 0, z = 0;
        for (int ci = 0; ci < 4; ++ci)
            for (int kw = 0; kw < 3; ++kw) {
                float v = wc[ci * 9 + kw];
                int b = kw * 4 + ci;
                s |= (v > 0.f  ? 1u : 0u) << b;
                z |= (v != 0.f ? 1u : 0u) << b;
            }
        ws_l[j][r] = s; wz_l[j][r] = z;
    }

    // --- BN constants (strict np fp32 chain), block-uniform -> SGPRs. ---
    float inv[4], bias[4];
#pragma unroll
    for (int ci = 0; ci < 4; ++ci) {
        int c = g * 4 + ci;
        float s  = sqrtf(var[c] + EPS);   // correctly rounded
        float r  = 1.0f / s;              // correctly rounded
        float iv = mul_rn(gamma[c], r);
        inv[ci]  = rfl_f(iv);
        bias[ci] = rfl_f(sub_rn(beta[c], mul_rn(mean[c], iv)));
    }

    // --- Phase A: stage 29 input rows as sign/nz nibbles (no barrier before:
    //     u16 writes to words 0..6 are disjoint from the zeroing above). ---
    for (int task = tid; task < ATASKS; task += 256) {
        int ar = task / 14;
        int cg = task - ar * 14;
        int off = (rowbase + ar) * W + cg * 4;
        uint32_t s16 = 0, z16 = 0;
#pragma unroll
        for (int ci = 0; ci < 4; ++ci) {
            const float4 v = *reinterpret_cast<const float4*>(
                Xn + (size_t)(g * 4 + ci) * HW + off);
            float t0 = add_rn_sv(bias[ci], mul_rn_sv(inv[ci], v.x));
            float t1 = add_rn_sv(bias[ci], mul_rn_sv(inv[ci], v.y));
            float t2 = add_rn_sv(bias[ci], mul_rn_sv(inv[ci], v.z));
            float t3 = add_rn_sv(bias[ci], mul_rn_sv(inv[ci], v.w));
            s16 |= ((t0 > 0.f ? 1u : 0u) << ci)        | ((t1 > 0.f ? 1u : 0u) << (4 + ci))
                 | ((t2 > 0.f ? 1u : 0u) << (8 + ci))  | ((t3 > 0.f ? 1u : 0u) << (12 + ci));
            z16 |= ((t0 != 0.f ? 1u : 0u) << ci)       | ((t1 != 0.f ? 1u : 0u) << (4 + ci))
                 | ((t2 != 0.f ? 1u : 0u) << (8 + ci)) | ((t3 != 0.f ? 1u : 0u) << (12 + ci));
        }
        int rt = ar + rtoff;
        reinterpret_cast<uint16_t*>(&s_tile[rt * ROWW])[cg] = (uint16_t)s16;
        reinterpret_cast<uint16_t*>(&z_tile[rt * ROWW])[cg] = (uint16_t)z16;
    }

    __syncthreads();                      // the ONLY barrier: tile + weights ready

    // Weight masks to SGPRs — AFTER the barrier (only wave 0 wrote ws_l/wz_l;
    // pre-barrier reads from other waves were round-6's correctness bug).
    uint32_t wsj[4][3], wzj[4][3];
    bool full = true;
#pragma unroll
    for (int j = 0; j < 4; ++j)
#pragma unroll
        for (int r = 0; r < 3; ++r) {
            wsj[j][r] = __builtin_amdgcn_readfirstlane(ws_l[j][r]);
            wzj[j][r] = __builtin_amdgcn_readfirstlane(wz_l[j][r]);
            full = full && (wzj[j][r] == 0xFFFu);
        }

    // --- Phase B: 6 two-dword LDS reads, XNOR-popcount 4 filters x 4 px,
    //     shuffled float4 shortcut + store. ---
    for (int task = tid; task < BTASKS; task += 256) {
        int hl = task / 14;
        int cg = task - hl * 14;
        int w0 = cg * 4;
        size_t pbase = (size_t)(half * 28 + hl) * W + w0;

        // LDS reads issued first...
        uint64_t vs[3], vz[3];
        int off;
        if (w0 == 0) {
            off = 0;
#pragma unroll
            for (int r = 0; r < 3; ++r) {
                int base = (hl + r) * ROWW;
                vs[r] = (((uint64_t)s_tile[base] | ((uint64_t)s_tile[base + 1] << 32)) << 4);
                vz[r] = (((uint64_t)z_tile[base] | ((uint64_t)z_tile[base + 1] << 32)) << 4);
            }
        } else {
            int st = 4 * w0 - 4;
            int i0 = st >> 5;
            off = st & 31;
#pragma unroll
            for (int r = 0; r < 3; ++r) {
                int base = (hl + r) * ROWW + i0;
                vs[r] = ((uint64_t)s_tile[base] | ((uint64_t)s_tile[base + 1] << 32));
                vz[r] = ((uint64_t)z_tile[base] | ((uint64_t)z_tile[base + 1] << 32));
            }
        }

        // ...then shortcut loads (L2 hits after XCD swizzle); the popcount
        // block below covers both latencies.
        float4 sc[4];
#pragma unroll
        for (int j = 0; j < 4; ++j)
            sc[j] = *reinterpret_cast<const float4*>(Xn + (size_t)(j * 64 + g) * HW + pbase);

        int res[4][4];
        if (full) {
#pragma unroll
            for (int k = 0; k < 4; ++k) {
                int sh = off + 4 * k;
                uint32_t s0 = (uint32_t)(vs[0] >> sh) & 0xFFFu;
                uint32_t s1 = (uint32_t)(vs[1] >> sh) & 0xFFFu;
                uint32_t s2 = (uint32_t)(vs[2] >> sh) & 0xFFFu;
                uint32_t z0 = (uint32_t)(vz[0] >> sh) & 0xFFFu;
                uint32_t z1 = (uint32_t)(vz[1] >> sh) & 0xFFFu;
                uint32_t z2 = (uint32_t)(vz[2] >> sh) & 0xFFFu;
                int vb = __popc(z0) + __popc(z1) + __popc(z2);
#pragma unroll
                for (int j = 0; j < 4; ++j) {
                    int pc = __popc((s0 ^ wsj[j][0]) & z0)
                           + __popc((s1 ^ wsj[j][1]) & z1)
                           + __popc((s2 ^ wsj[j][2]) & z2);
                    res[j][k] = vb - 2 * pc;
                }
            }
        } else {
#pragma unroll
            for (int k = 0; k < 4; ++k) {
                int sh = off + 4 * k;
                uint32_t s0 = (uint32_t)(vs[0] >> sh) & 0xFFFu;
                uint32_t s1 = (uint32_t)(vs[1] >> sh) & 0xFFFu;
                uint32_t s2 = (uint32_t)(vs[2] >> sh) & 0xFFFu;
                uint32_t z0 = (uint32_t)(vz[0] >> sh) & 0xFFFu;
                uint32_t z1 = (uint32_t)(vz[1] >> sh) & 0xFFFu;
                uint32_t z2 = (uint32_t)(vz[2] >> sh) & 0xFFFu;
#pragma unroll
                for (int j = 0; j < 4; ++j) {
                    uint32_t m0 = z0 & wzj[j][0];
                    uint32_t m1 = z1 & wzj[j][1];
                    uint32_t m2 = z2 & wzj[j][2];
                    int vb = __popc(m0) + __popc(m1) + __popc(m2);
                    int pc = __popc((s0 ^ wsj[j][0]) & m0)
                           + __popc((s1 ^ wsj[j][1]) & m1)
                           + __popc((s2 ^ wsj[j][2]) & m2);
                    res[j][k] = vb - 2 * pc;
                }
            }
        }

        // Epilogue: shuffled channel c' = j*64 + g; float4 shortcut + store.
#pragma unroll
        for (int j = 0; j < 4; ++j) {
            size_t cofs = (size_t)(j * 64 + g) * HW + pbase;
            float4 o;
            o.x = add_rn((float)res[j][0], sc[j].x);
            o.y = add_rn((float)res[j][1], sc[j].y);
            o.z = add_rn((float)res[j][2], sc[j].z);
            o.w = add_rn((float)res[j][3], sc[j].w);
            *reinterpret_cast<float4*>(On + cofs) = o;
        }
    }
}

// ---------------------------------------------------------------------------
extern "C" void kernel_launch(void* const* d_in, const int* in_sizes, int n_in,
                              void* d_out, int out_size, void* d_ws, size_t ws_size,
                              hipStream_t stream) {
    const float* X     = (const float*)d_in[0];
    const float* Wt    = (const float*)d_in[1];
    const float* gamma = (const float*)d_in[2];
    const float* beta  = (const float*)d_in[3];
    const float* mean  = (const float*)d_in[4];
    const float* var   = (const float*)d_in[5];
    float* out = (float*)d_out;

    int N = in_sizes[0] / IMG;        // 32

    // grid: n (32) x group (64) x row-half (2) = 4096 blocks, XCD-swizzled
    binconv_kernel<<<N * 64 * 2, 256, 0, stream>>>(X, Wt, gamma, beta, mean, var, out);
}

// Round 8
// 195.702 us; speedup vs baseline: 1.1287x; 1.0087x over previous
//
#include <hip/hip_runtime.h>
#include <stdint.h>

// Problem constants (fixed by the reference)
#define H 56
#define W 56
#define HW (H * W)          // 3136
#define CIN 256
#define IMG (CIN * HW)      // 802816 elements per image
#define EPS 1e-5f

#define ROWW 8              // u32 words per tile row: 32B = 64 nibbles
#define TR2 30              // tile rows: 28 outputs + 2 halo/padding
#define TSZ (TR2 * ROWW)    // 240 words per tile
#define ATASKS 406          // 29 staged input rows x 14 col-groups
#define BTASKS 392          // 28 output rows x 14 col-groups
#define NT 384              // 6 waves: ~1 task/thread in both phases

// Strict fp32 RN ops, immune to -ffp-contract (inline asm cannot be fused).
// The np reference's exact-zero BN outputs (sign->0) only reproduce with the
// two-rounding chain round(round(x*inv)+bias).
__device__ __forceinline__ float mul_rn(float a, float b) {
    float d; asm("v_mul_f32 %0, %1, %2" : "=v"(d) : "v"(a), "v"(b)); return d;
}
__device__ __forceinline__ float add_rn(float a, float b) {
    float d; asm("v_add_f32 %0, %1, %2" : "=v"(d) : "v"(a), "v"(b)); return d;
}
__device__ __forceinline__ float sub_rn(float a, float b) {
    float d; asm("v_sub_f32 %0, %1, %2" : "=v"(d) : "v"(a), "v"(b)); return d;
}
// Scalar-operand variants: BN constants are block-uniform -> SGPR (src0 may be
// scalar). Multiplication/addition commute bit-exactly in RN.
__device__ __forceinline__ float mul_rn_sv(float s, float v) {
    float d; asm("v_mul_f32 %0, %1, %2" : "=v"(d) : "s"(s), "v"(v)); return d;
}
__device__ __forceinline__ float add_rn_sv(float s, float v) {
    float d; asm("v_add_f32 %0, %1, %2" : "=v"(d) : "s"(s), "v"(v)); return d;
}
__device__ __forceinline__ float rfl_f(float x) {
    return __int_as_float(__builtin_amdgcn_readfirstlane(__float_as_int(x)));
}

// ---------------------------------------------------------------------------
// Fused: BN -> ternary sign -> XNOR-popcount grouped 3x3 conv -> shuffle -> +x
//
// Round-8 = round-7 with ONE change: block = 384 threads (6 waves), natural
// register allocation. Tasks/thread: A = 406/384 = 1.06, B = 392/384 = 1.02
// -> one full-utilization pass per phase, no half-empty second pass (R7's
// 256-thread shape ran 1.5x tasks/thread: every phase had a ~53%-utilization
// straggler pass gating block exit). R5 tried this shape but forced
// __launch_bounds__(384,8) -> spills; this is the clean run.
// Static occupancy: ~40 VGPR natural -> 5 blocks x 6 waves = 30/32 waves/CU.
//
// Retained from R7:
//  * XCD swizzle: all 128 blocks of plane n -> XCD n&7 (3.2 MB X-plane in
//    one 4 MiB XCD L2; shortcut re-read hits L2: FETCH 100->85 MB measured).
//  * Single-barrier: only pad row + word 7 of each row are zeroed (disjoint
//    from phase-A's u16 writes to words 0..6) -> no pre-phase-A barrier.
//  * Weight-mask SGPR hoist strictly AFTER the barrier (R6's race).
//  * NO forced min-waves launch_bounds (spill trigger in R2/R3/R5).
//
// LDS tile: 30 rows x 8 u32 of packed 4-bit nibbles (nibble w = 4 channel
// bits of pixel w). half0 stages input rows 0..28 at tile rows 1..29 (row 0
// = top pad); half1 stages rows 27..55 at tile rows 0..28 (row 29 = bottom
// pad). Pad row + word 7 (nibbles 56..63) are zero => z-plane zeros subsume
// all geometric padding.
// ---------------------------------------------------------------------------

__global__ __launch_bounds__(NT)
void binconv_kernel(const float* __restrict__ X,
                    const float* __restrict__ Wt,
                    const float* __restrict__ gamma,
                    const float* __restrict__ beta,
                    const float* __restrict__ mean,
                    const float* __restrict__ var,
                    float* __restrict__ out) {
    __shared__ uint32_t s_tile[TSZ];      // sign nibbles
    __shared__ uint32_t z_tile[TSZ];      // nonzero nibbles
    __shared__ uint32_t ws_l[4][3];       // weight sign rows (12-bit)
    __shared__ uint32_t wz_l[4][3];       // weight nz   rows (12-bit)

    // XCD-swizzled decode: bx = (n>>3)<<10 | (g*2+half)<<3 | (n&7).
    // Dispatch round-robins blocks over XCDs by bx, so bx%8 pins the XCD.
    const int bx   = blockIdx.x;
    const int n    = ((bx >> 10) << 3) | (bx & 7);
    const int rem  = (bx >> 3) & 127;
    const int g    = rem >> 1;
    const int half = rem & 1;
    const int tid  = threadIdx.x;

    const int rowbase = half * 27;        // half0: rows 0..28, half1: 27..55
    const int rtoff   = 1 - half;         // tile row = ar + rtoff
    const int padrow  = half * 29;        // unwritten tile row (0 or 29)

    const float* Xn = X   + (size_t)n * IMG;
    float*       On = out + (size_t)n * IMG;

    // --- Targeted zeroing: ONLY the bytes phase A never writes. ---
    // tasks 0..29: word 7 of tile row t   (both planes)
    // tasks 30..36: words 0..6 of pad row (both planes)
    if (tid < 37) {
        int idx = (tid < 30) ? (tid * ROWW + 7) : (padrow * ROWW + (tid - 30));
        s_tile[idx] = 0u;
        z_tile[idx] = 0u;
    }

    // --- Weight pack, spread over 12 threads (filter j, row r each). ---
    // bit = kw*4 + ci  (kw aligns with window nibble: w-1, w, w+1).
    if (tid < 12) {
        int j = tid / 3, r = tid - j * 3;
        const float* wc = Wt + (size_t)(g * 4 + j) * 36 + r * 3;  // [ci][kh][kw]
        uint32_t s = 0, z = 0;
        for (int ci = 0; ci < 4; ++ci)
            for (int kw = 0; kw < 3; ++kw) {
                float v = wc[ci * 9 + kw];
                int b = kw * 4 + ci;
                s |= (v > 0.f  ? 1u : 0u) << b;
                z |= (v != 0.f ? 1u : 0u) << b;
            }
        ws_l[j][r] = s; wz_l[j][r] = z;
    }

    // --- BN constants (strict np fp32 chain), block-uniform -> SGPRs. ---
    float inv[4], bias[4];
#pragma unroll
    for (int ci = 0; ci < 4; ++ci) {
        int c = g * 4 + ci;
        float s  = sqrtf(var[c] + EPS);   // correctly rounded
        float r  = 1.0f / s;              // correctly rounded
        float iv = mul_rn(gamma[c], r);
        inv[ci]  = rfl_f(iv);
        bias[ci] = rfl_f(sub_rn(beta[c], mul_rn(mean[c], iv)));
    }

    // --- Phase A: stage 29 input rows as sign/nz nibbles (no barrier before:
    //     u16 writes to words 0..6 are disjoint from the zeroing above).
    //     1.06 tasks/thread: only threads 0..21 take a second task. ---
    for (int task = tid; task < ATASKS; task += NT) {
        int ar = task / 14;
        int cg = task - ar * 14;
        int off = (rowbase + ar) * W + cg * 4;
        uint32_t s16 = 0, z16 = 0;
#pragma unroll
        for (int ci = 0; ci < 4; ++ci) {
            const float4 v = *reinterpret_cast<const float4*>(
                Xn + (size_t)(g * 4 + ci) * HW + off);
            float t0 = add_rn_sv(bias[ci], mul_rn_sv(inv[ci], v.x));
            float t1 = add_rn_sv(bias[ci], mul_rn_sv(inv[ci], v.y));
            float t2 = add_rn_sv(bias[ci], mul_rn_sv(inv[ci], v.z));
            float t3 = add_rn_sv(bias[ci], mul_rn_sv(inv[ci], v.w));
            s16 |= ((t0 > 0.f ? 1u : 0u) << ci)        | ((t1 > 0.f ? 1u : 0u) << (4 + ci))
                 | ((t2 > 0.f ? 1u : 0u) << (8 + ci))  | ((t3 > 0.f ? 1u : 0u) << (12 + ci));
            z16 |= ((t0 != 0.f ? 1u : 0u) << ci)       | ((t1 != 0.f ? 1u : 0u) << (4 + ci))
                 | ((t2 != 0.f ? 1u : 0u) << (8 + ci)) | ((t3 != 0.f ? 1u : 0u) << (12 + ci));
        }
        int rt = ar + rtoff;
        reinterpret_cast<uint16_t*>(&s_tile[rt * ROWW])[cg] = (uint16_t)s16;
        reinterpret_cast<uint16_t*>(&z_tile[rt * ROWW])[cg] = (uint16_t)z16;
    }

    __syncthreads();                      // the ONLY barrier: tile + weights ready

    // Weight masks to SGPRs — AFTER the barrier (only wave 0 wrote ws_l/wz_l;
    // pre-barrier reads from other waves were round-6's correctness bug).
    uint32_t wsj[4][3], wzj[4][3];
    bool full = true;
#pragma unroll
    for (int j = 0; j < 4; ++j)
#pragma unroll
        for (int r = 0; r < 3; ++r) {
            wsj[j][r] = __builtin_amdgcn_readfirstlane(ws_l[j][r]);
            wzj[j][r] = __builtin_amdgcn_readfirstlane(wz_l[j][r]);
            full = full && (wzj[j][r] == 0xFFFu);
        }

    // --- Phase B: 1.02 tasks/thread (threads 0..7 take a second). ---
    for (int task = tid; task < BTASKS; task += NT) {
        int hl = task / 14;
        int cg = task - hl * 14;
        int w0 = cg * 4;
        size_t pbase = (size_t)(half * 28 + hl) * W + w0;

        // LDS reads issued first...
        uint64_t vs[3], vz[3];
        int off;
        if (w0 == 0) {
            off = 0;
#pragma unroll
            for (int r = 0; r < 3; ++r) {
                int base = (hl + r) * ROWW;
                vs[r] = (((uint64_t)s_tile[base] | ((uint64_t)s_tile[base + 1] << 32)) << 4);
                vz[r] = (((uint64_t)z_tile[base] | ((uint64_t)z_tile[base + 1] << 32)) << 4);
            }
        } else {
            int st = 4 * w0 - 4;
            int i0 = st >> 5;
            off = st & 31;
#pragma unroll
            for (int r = 0; r < 3; ++r) {
                int base = (hl + r) * ROWW + i0;
                vs[r] = ((uint64_t)s_tile[base] | ((uint64_t)s_tile[base + 1] << 32));
                vz[r] = ((uint64_t)z_tile[base] | ((uint64_t)z_tile[base + 1] << 32));
            }
        }

        // ...then shortcut loads (L2 hits after XCD swizzle); the popcount
        // block below covers both latencies.
        float4 sc[4];
#pragma unroll
        for (int j = 0; j < 4; ++j)
            sc[j] = *reinterpret_cast<const float4*>(Xn + (size_t)(j * 64 + g) * HW + pbase);

        int res[4][4];
        if (full) {
#pragma unroll
            for (int k = 0; k < 4; ++k) {
                int sh = off + 4 * k;
                uint32_t s0 = (uint32_t)(vs[0] >> sh) & 0xFFFu;
                uint32_t s1 = (uint32_t)(vs[1] >> sh) & 0xFFFu;
                uint32_t s2 = (uint32_t)(vs[2] >> sh) & 0xFFFu;
                uint32_t z0 = (uint32_t)(vz[0] >> sh) & 0xFFFu;
                uint32_t z1 = (uint32_t)(vz[1] >> sh) & 0xFFFu;
                uint32_t z2 = (uint32_t)(vz[2] >> sh) & 0xFFFu;
                int vb = __popc(z0) + __popc(z1) + __popc(z2);
#pragma unroll
                for (int j = 0; j < 4; ++j) {
                    int pc = __popc((s0 ^ wsj[j][0]) & z0)
                           + __popc((s1 ^ wsj[j][1]) & z1)
                           + __popc((s2 ^ wsj[j][2]) & z2);
                    res[j][k] = vb - 2 * pc;
                }
            }
        } else {
#pragma unroll
            for (int k = 0; k < 4; ++k) {
                int sh = off + 4 * k;
                uint32_t s0 = (uint32_t)(vs[0] >> sh) & 0xFFFu;
                uint32_t s1 = (uint32_t)(vs[1] >> sh) & 0xFFFu;
                uint32_t s2 = (uint32_t)(vs[2] >> sh) & 0xFFFu;
                uint32_t z0 = (uint32_t)(vz[0] >> sh) & 0xFFFu;
                uint32_t z1 = (uint32_t)(vz[1] >> sh) & 0xFFFu;
                uint32_t z2 = (uint32_t)(vz[2] >> sh) & 0xFFFu;
#pragma unroll
                for (int j = 0; j < 4; ++j) {
                    uint32_t m0 = z0 & wzj[j][0];
                    uint32_t m1 = z1 & wzj[j][1];
                    uint32_t m2 = z2 & wzj[j][2];
                    int vb = __popc(m0) + __popc(m1) + __popc(m2);
                    int pc = __popc((s0 ^ wsj[j][0]) & m0)
                           + __popc((s1 ^ wsj[j][1]) & m1)
                           + __popc((s2 ^ wsj[j][2]) & m2);
                    res[j][k] = vb - 2 * pc;
                }
            }
        }

        // Epilogue: shuffled channel c' = j*64 + g; float4 shortcut + store.
#pragma unroll
        for (int j = 0; j < 4; ++j) {
            size_t cofs = (size_t)(j * 64 + g) * HW + pbase;
            float4 o;
            o.x = add_rn((float)res[j][0], sc[j].x);
            o.y = add_rn((float)res[j][1], sc[j].y);
            o.z = add_rn((float)res[j][2], sc[j].z);
            o.w = add_rn((float)res[j][3], sc[j].w);
            *reinterpret_cast<float4*>(On + cofs) = o;
        }
    }
}

// ---------------------------------------------------------------------------
extern "C" void kernel_launch(void* const* d_in, const int* in_sizes, int n_in,
                              void* d_out, int out_size, void* d_ws, size_t ws_size,
                              hipStream_t stream) {
    const float* X     = (const float*)d_in[0];
    const float* Wt    = (const float*)d_in[1];
    const float* gamma = (const float*)d_in[2];
    const float* beta  = (const float*)d_in[3];
    const float* mean  = (const float*)d_in[4];
    const float* var   = (const float*)d_in[5];
    float* out = (float*)d_out;

    int N = in_sizes[0] / IMG;        // 32

    // grid: n (32) x group (64) x row-half (2) = 4096 blocks, XCD-swizzled
    binconv_kernel<<<N * 64 * 2, NT, 0, stream>>>(X, Wt, gamma, beta, mean, var, out);
}